// Round 6
// baseline (94.265 us; speedup 1.0000x reference)
//
#include <hip/hip_runtime.h>
#include <stdint.h>

// ---------------------------------------------------------------------------
// NeighborSearch: data[n,3], queries[m,3], radius scalar.
// Out layout (int32): [0, m*n)   neighbors_index (compacted front, -1 pad)
//                     [m*n, m*n+m+1) row_splits (exclusive prefix of counts)
//
// Fast path (n==m==8192), serial 3-kernel pipeline, each in ONE regime:
//   K1 count_masks: wave-per-query, LDS-staged points -> per-query 64b chunk
//      masks in d_ws + counts. cnt accumulates popcll(ballot) per chunk, so
//      it is ALREADY the full per-query count on every lane (R5 bug: an extra
//      shfl reduction made counts 64x too large).
//   K2 scan: exclusive prefix -> row_splits (in d_out).
//   K3 fill_emit: emit indices into [0,L) from masks; block 0 aligns [L,Lr);
//      grid-stride int4 -1 fill over [Lr, m*n). Disjoint pure-write stream.
// ---------------------------------------------------------------------------

#define N8 8192

__device__ __forceinline__ float next_up(float x) {
    return __uint_as_float(__float_as_uint(x) + 1u);
}
__device__ __forceinline__ float next_down(float x) {
    return __uint_as_float(__float_as_uint(x) - 1u);
}

// Largest float T such that correctly-rounded sqrt(T) <= r (r > 0).
// (u <= T) <=> (sqrt_rn(max(u,0)) <= r), since sqrt_rn is monotone.
__device__ __forceinline__ float sq_threshold(float r) {
    float T = __fmul_rn(r, r);
    while (__fsqrt_rn(T) > r) T = next_down(T);
    while (__fsqrt_rn(next_up(T)) <= r) T = next_up(T);
    return T;
}

// Reference arithmetic, exactly (no contraction):
// d2 = (dx*dx + dy*dy) + dz*dz ; dot = fma(qz,dz, fma(qy,dy, qx*dx))
// u  = (q2 + d2) - 2*dot
__device__ __forceinline__ float pair_metric_d2(float qx, float qy, float qz,
                                                float q2, float dx, float dy,
                                                float dz, float d2) {
    float dot = __builtin_fmaf(qz, dz, __builtin_fmaf(qy, dy, __fmul_rn(qx, dx)));
    return __fsub_rn(__fadd_rn(q2, d2), __fmul_rn(2.0f, dot));
}
__device__ __forceinline__ float pair_metric(float qx, float qy, float qz, float q2,
                                             float dx, float dy, float dz) {
    float d2 = __fadd_rn(__fadd_rn(__fmul_rn(dx, dx), __fmul_rn(dy, dy)),
                         __fmul_rn(dz, dz));
    return pair_metric_d2(qx, qy, qz, q2, dx, dy, dz, d2);
}

// ========================= fast path (8192 x 8192) =========================

// Grid: 2048 x 256. Wave w of block b owns query q = b*4+w.
// masks[q*128 + c] = mask of points [c*64,(c+1)*64). VERBATIM R4 count role.
__global__ __launch_bounds__(256) void count_masks(
    const float* __restrict__ data, const float* __restrict__ queries,
    const float* __restrict__ radius_p,
    unsigned long long* __restrict__ masks, int* __restrict__ counts) {
    __shared__ float4 pts[512];

    int wave = threadIdx.x >> 6;
    int lane = threadIdx.x & 63;
    int q = blockIdx.x * 4 + wave;

    float r = radius_p[0];
    float T = sq_threshold(r);
    float qx = queries[3 * q + 0], qy = queries[3 * q + 1], qz = queries[3 * q + 2];
    float q2 = __fadd_rn(__fadd_rn(__fmul_rn(qx, qx), __fmul_rn(qy, qy)),
                         __fmul_rn(qz, qz));

    unsigned long long mlo = 0, mhi = 0;  // chunk c's mask parked in lane (c&63)
    int cnt = 0;                          // popcll(ballot): full count per lane

    for (int rd = 0; rd < 16; ++rd) {     // 16 rounds x 512 points
        int p0 = rd * 512;
        __syncthreads();
        for (int p = threadIdx.x; p < 512; p += 256) {
            float dx = data[3 * (p0 + p) + 0];
            float dy = data[3 * (p0 + p) + 1];
            float dz = data[3 * (p0 + p) + 2];
            float d2 = __fadd_rn(__fadd_rn(__fmul_rn(dx, dx), __fmul_rn(dy, dy)),
                                 __fmul_rn(dz, dz));
            pts[p] = make_float4(dx, dy, dz, d2);
        }
        __syncthreads();
#pragma unroll
        for (int cc = 0; cc < 8; ++cc) {
            float4 d = pts[cc * 64 + lane];
            float u = pair_metric_d2(qx, qy, qz, q2, d.x, d.y, d.z, d.w);
            unsigned long long mask = __ballot(u <= T);
            int c = rd * 8 + cc;
            if (lane == (c & 63)) {
                if (c < 64) mlo = mask; else mhi = mask;
            }
            cnt += __popcll(mask);
        }
    }
    masks[(size_t)q * 128 + lane] = mlo;        // coalesced 512B per wave
    masks[(size_t)q * 128 + 64 + lane] = mhi;
    if (lane == 0) counts[q] = cnt;             // NO reduction: cnt is complete
}

// Exclusive scan of counts[0..m) -> rs[0..m]. One block, m <= 8192.
__global__ __launch_bounds__(1024) void scan_kernel2(const int* __restrict__ counts,
                                                     int* __restrict__ rs, int m) {
    __shared__ int part[1024];
    int t = threadIdx.x;
    int base = t * 8;
    int c[8];
    int s = 0;
    for (int k = 0; k < 8; ++k) {
        int p = base + k;
        c[k] = (p < m) ? counts[p] : 0;
        s += c[k];
    }
    part[t] = s;
    __syncthreads();
    for (int off = 1; off < 1024; off <<= 1) {
        int v = 0;
        if (t >= off) v = part[t - off];
        __syncthreads();
        if (t >= off) part[t] += v;
        __syncthreads();
    }
    int run = (t == 0) ? 0 : part[t - 1];
    for (int k = 0; k < 8; ++k) {
        int p = base + k;
        if (p < m) rs[p] = run;
        run += c[k];
    }
    if (t == 1023) rs[m] = part[1023];
}

// Grid: 2048 x 256. Wave w of block b emits query q = b*4+w into [0,L);
// then all threads grid-stride -1 over [Lr, 64M). Disjoint writes.
__global__ __launch_bounds__(256) void fill_emit(
    const unsigned long long* __restrict__ masks, const int* __restrict__ rs,
    int* __restrict__ out_idx) {
    int wave = threadIdx.x >> 6;
    int lane = threadIdx.x & 63;
    int q = blockIdx.x * 4 + wave;

    // ---- emit (positions < L), verbatim R4 emit_from_masks ----
    unsigned long long lo = masks[(size_t)q * 128 + lane];
    unsigned long long hi = masks[(size_t)q * 128 + 64 + lane];
    int plo = __popcll(lo), phi = __popcll(hi);
    int ilo = plo, ihi = phi;
    for (int off = 1; off < 64; off <<= 1) {
        int a = __shfl_up(ilo, off, 64);
        int b = __shfl_up(ihi, off, 64);
        if (lane >= off) { ilo += a; ihi += b; }
    }
    int total_lo = __shfl(ilo, 63, 64);
    int base = rs[q];
    int pos_lo = base + ilo - plo;
    int pos_hi = base + total_lo + ihi - phi;
    int jb_lo = lane * 64, jb_hi = (64 + lane) * 64;
    while (lo) {
        int b = __builtin_ctzll(lo);
        out_idx[pos_lo++] = jb_lo + b;
        lo &= lo - 1;
    }
    while (hi) {
        int b = __builtin_ctzll(hi);
        out_idx[pos_hi++] = jb_hi + b;
        hi &= hi - 1;
    }

    // ---- fill (positions >= L) ----
    int L = rs[N8];                       // uniform load, L2-hot
    int Lr = (L + 3) & ~3;                // int4-align the fill start
    if (blockIdx.x == 0 && (int)threadIdx.x < (Lr - L))
        out_idx[L + threadIdx.x] = -1;
    int4* out4 = (int4*)out_idx;
    const int4 v = make_int4(-1, -1, -1, -1);
    const size_t n4 = (size_t)N8 * N8 / 4;       // 16,777,216
    size_t i = (size_t)(Lr >> 2) + (size_t)blockIdx.x * 256 + threadIdx.x;
    const size_t stride = 2048ull * 256ull;
    for (; i < n4; i += stride) out4[i] = v;
}

// ====================== generic fallback (round-1 path) ======================

__global__ __launch_bounds__(256) void fill_kernel(int* __restrict__ out, size_t total) {
    size_t n4 = total >> 2;
    int4* out4 = (int4*)out;
    size_t i = (size_t)blockIdx.x * blockDim.x + threadIdx.x;
    size_t stride = (size_t)gridDim.x * blockDim.x;
    const int4 v = make_int4(-1, -1, -1, -1);
    for (; i < n4; i += stride) out4[i] = v;
    if (blockIdx.x == 0 && threadIdx.x == 0) {
        for (size_t k = n4 << 2; k < total; ++k) out[k] = -1;
    }
}

__global__ __launch_bounds__(256) void count_kernel(
    const float* __restrict__ data, const float* __restrict__ queries,
    const float* __restrict__ radius_p, int n, int m, int* __restrict__ counts) {
    int q = (blockIdx.x * blockDim.x + threadIdx.x) >> 6;
    int lane = threadIdx.x & 63;
    if (q >= m) return;
    float r = radius_p[0];
    float T = sq_threshold(r);
    float qx = queries[3 * q + 0], qy = queries[3 * q + 1], qz = queries[3 * q + 2];
    float q2 = __fadd_rn(__fadd_rn(__fmul_rn(qx, qx), __fmul_rn(qy, qy)),
                         __fmul_rn(qz, qz));
    int cnt = 0;
    for (int j = lane; j < n; j += 64) {
        float u = pair_metric(qx, qy, qz, q2, data[3 * j], data[3 * j + 1], data[3 * j + 2]);
        if (u <= T) cnt++;
    }
    for (int off = 32; off > 0; off >>= 1) cnt += __shfl_down(cnt, off, 64);
    if (lane == 0) counts[q] = cnt;
}

__global__ __launch_bounds__(256) void emit_kernel(
    const float* __restrict__ data, const float* __restrict__ queries,
    const float* __restrict__ radius_p, int n, int m,
    const int* __restrict__ row_splits, int* __restrict__ out_idx) {
    int q = (blockIdx.x * blockDim.x + threadIdx.x) >> 6;
    int lane = threadIdx.x & 63;
    if (q >= m) return;
    float r = radius_p[0];
    float T = sq_threshold(r);
    float qx = queries[3 * q + 0], qy = queries[3 * q + 1], qz = queries[3 * q + 2];
    float q2 = __fadd_rn(__fadd_rn(__fmul_rn(qx, qx), __fmul_rn(qy, qy)),
                         __fmul_rn(qz, qz));
    int base = row_splits[q];
    unsigned long long lane_mask_lt = (lane == 0) ? 0ULL : (~0ULL >> (64 - lane));
    for (int j0 = 0; j0 < n; j0 += 64) {
        int j = j0 + lane;
        bool pred = false;
        if (j < n) {
            float u = pair_metric(qx, qy, qz, q2, data[3 * j], data[3 * j + 1], data[3 * j + 2]);
            pred = (u <= T);
        }
        unsigned long long mask = __ballot(pred);
        if (pred) {
            int pos = base + __popcll(mask & lane_mask_lt);
            out_idx[pos] = j;
        }
        base += __popcll(mask);
    }
}

// ===========================================================================

extern "C" void kernel_launch(void* const* d_in, const int* in_sizes, int n_in,
                              void* d_out, int out_size, void* d_ws, size_t ws_size,
                              hipStream_t stream) {
    const float* data = (const float*)d_in[0];
    const float* queries = (const float*)d_in[1];
    const float* radius = (const float*)d_in[2];
    int n = in_sizes[0] / 3;
    int m = in_sizes[1] / 3;
    int* out = (int*)d_out;
    size_t idx_count = (size_t)m * (size_t)n;
    int* row = out + idx_count;  // m+1 ints

    size_t need = (size_t)m * 128 * 8 + (size_t)m * 4;
    bool fast = (n == N8) && (m == N8) && (ws_size >= need);

    if (fast) {
        unsigned long long* masks = (unsigned long long*)d_ws;
        int* counts = (int*)((char*)d_ws + (size_t)m * 128 * 8);
        count_masks<<<2048, 256, 0, stream>>>(data, queries, radius, masks, counts);
        scan_kernel2<<<1, 1024, 0, stream>>>(counts, row, m);
        fill_emit<<<2048, 256, 0, stream>>>(masks, row, out);
    } else {
        fill_kernel<<<2048, 256, 0, stream>>>(out, idx_count);
        int blocks = (m * 64 + 255) / 256;
        count_kernel<<<blocks, 256, 0, stream>>>(data, queries, radius, n, m, row);
        scan_kernel2<<<1, 1024, 0, stream>>>(row, row, m);
        emit_kernel<<<blocks, 256, 0, stream>>>(data, queries, radius, n, m, row, out);
    }
}